// Round 8
// baseline (90.931 us; speedup 1.0000x reference)
//
#include <hip/hip_runtime.h>
#include <hip/hip_bf16.h>
#include <math.h>

typedef __bf16 bf16;
typedef __attribute__((ext_vector_type(8))) bf16 bf16x8;
typedef __attribute__((ext_vector_type(2))) bf16 bf16x2;
typedef __attribute__((ext_vector_type(16))) float f32x16;
typedef __attribute__((ext_vector_type(4))) unsigned int uint4v;

#define SQ 2048
#define DH 64
#define NH 16
#define QBLK 64
#define KVT 64
#define NKVT (SQ / KVT)
#define LOG2E 1.44269504088896340736f

__device__ __forceinline__ float fast_exp2(float x) {
#if __has_builtin(__builtin_amdgcn_exp2f)
    return __builtin_amdgcn_exp2f(x);
#else
    return exp2f(x);
#endif
}

__device__ __forceinline__ unsigned pkbf16(float a, float b) {
    union { bf16x2 h; unsigned u; } x;
    x.h = (bf16x2){(bf16)a, (bf16)b};
    return x.u;
}

// permlane32_swap: a' = [a.lo | b.lo], b' = [a.hi | b.hi]
#if __has_builtin(__builtin_amdgcn_permlane32_swap)
__device__ __forceinline__ void plswap(unsigned &a, unsigned &b) {
    typedef __attribute__((ext_vector_type(2))) unsigned int uint2v;
    uint2v r = __builtin_amdgcn_permlane32_swap(a, b, false, false);
    a = r[0]; b = r[1];
}
#else
__device__ __forceinline__ void plswap(unsigned &a, unsigned &b) {
    asm volatile("v_permlane32_swap_b32 %0, %1" : "+v"(a), "+v"(b));
}
#endif

union FragU { uint4v u; bf16x8 b; };

// ---------- prepass: K fp32 -> bf16 row-major; V fp32 -> V^T bf16 ----------
__global__ __launch_bounds__(256)
void alibi_prep_kernel(const float* __restrict__ K, const float* __restrict__ V,
                       bf16* __restrict__ Kb, bf16* __restrict__ Vtb) {
    __shared__ bf16 lt[64][72];
    const int t  = threadIdx.x;
    const int s0 = blockIdx.x * 64;
    const int bh = blockIdx.y;
    if (blockIdx.z == 0) {
        const float* src = K + (size_t)bh * SQ * DH + (size_t)s0 * DH;
        bf16* dst = Kb + (size_t)bh * SQ * DH + (size_t)s0 * DH;
#pragma unroll
        for (int i = 0; i < 2; ++i) {
            int idx = t + 256 * i;
            int row = idx >> 3, c8 = idx & 7;
            const float* p = src + row * DH + c8 * 8;
            float4 a = *(const float4*)p, b = *(const float4*)(p + 4);
            bf16x8 pk = {(bf16)a.x,(bf16)a.y,(bf16)a.z,(bf16)a.w,
                         (bf16)b.x,(bf16)b.y,(bf16)b.z,(bf16)b.w};
            *(bf16x8*)(dst + row * DH + c8 * 8) = pk;
        }
    } else {
        const float* src = V + (size_t)bh * SQ * DH + (size_t)s0 * DH;
#pragma unroll
        for (int i = 0; i < 2; ++i) {
            int idx = t + 256 * i;
            int row = idx >> 3, c8 = idx & 7;
            const float* p = src + row * DH + c8 * 8;
            float4 a = *(const float4*)p, b = *(const float4*)(p + 4);
            bf16 e[8] = {(bf16)a.x,(bf16)a.y,(bf16)a.z,(bf16)a.w,
                         (bf16)b.x,(bf16)b.y,(bf16)b.z,(bf16)b.w};
#pragma unroll
            for (int j = 0; j < 8; ++j) lt[c8 * 8 + j][row] = e[j];
        }
        __syncthreads();
        bf16* dst = Vtb + (size_t)bh * DH * SQ;
#pragma unroll
        for (int i = 0; i < 2; ++i) {
            int idx = t + 256 * i;
            int d = idx >> 3, c8 = idx & 7;
            *(bf16x8*)(dst + (size_t)d * SQ + s0 + c8 * 8) = *(const bf16x8*)&lt[d][c8 * 8];
        }
    }
}

// ---------- main attention kernel (banded, KV-parallel waves, NO LDS staging) ----------
__global__ __launch_bounds__(256, 4)
void alibi_attn_kernel(const float* __restrict__ Q, const bf16* __restrict__ Kb,
                       const bf16* __restrict__ Vtb, float* __restrict__ Out) {
    __shared__ float ex[2][64][36];      // parity-combine exchange only (18.4 KB)
    const int tid   = threadIdx.x;
    const int lane  = tid & 63;
    const int wave  = tid >> 6;
    const int par   = wave >> 1;    // KV parity this wave computes
    const int qhalf = wave & 1;     // q-half this wave computes
    const int r32   = lane & 31;
    const int hi    = lane >> 5;

    // ---- heavy-first quartet mapping: blocks {i, 256+i, 512+i, 768+i} share a CU
    //      (round-robin heuristic; speed-only) and get ranks {i, 511-i, 512+i, 1023-i} ----
    const int b  = blockIdx.x;           // 0..1023
    const int qd = b >> 8, i = b & 255;
    int r;
    if      (qd == 0) r = i;
    else if (qd == 1) r = 511 - i;
    else if (qd == 2) r = 512 + i;
    else              r = 1023 - i;
    const int h   = 15 - (r >> 6);       // 64 ranks per head, widest bands first
    const int sub = r & 63;
    const int bh  = (sub >> 5) * NH + h; // batch = sub>>5
    const int q0  = (sub & 31) * QBLK;

    const float slope2  = exp2f(-0.5f * (float)(h + 1)) * LOG2E;
    const float SLOPE2N = -slope2;
    const float QSCALE  = 0.125f * LOG2E;

    // ---- ALiBi band: drop tiles with slope2*minDelta > 24 (rel err < 1e-5) ----
    const int D = (int)(24.0f / slope2);
    const int a0 = q0 - D;
    const int tmin = (a0 <= 0) ? 0 : (a0 >> 6);
    const int tmax = min(NKVT - 1, (q0 + QBLK - 1 + D) >> 6);

    const size_t base = (size_t)bh * SQ * DH;
    const float* Qp = Q + base;
    const bf16*  Kp = Kb + base;
    const bf16*  Vp = Vtb + base;        // [DH][SQ]
    float*       Op = Out + base;

    // Q B-frag (pre-scaled): lane holds Q[q=qrow][dstep*16 + hi*8 + j]
    const int qrow = q0 + qhalf * 32 + r32;
    bf16x8 qfrag[4];
#pragma unroll
    for (int dstep = 0; dstep < 4; ++dstep) {
        const float* sq = Qp + (size_t)qrow * DH + dstep * 16 + hi * 8;
        float4 a = *(const float4*)sq, bb = *(const float4*)(sq + 4);
        qfrag[dstep] = (bf16x8){(bf16)(a.x*QSCALE),(bf16)(a.y*QSCALE),
                                (bf16)(a.z*QSCALE),(bf16)(a.w*QSCALE),
                                (bf16)(bb.x*QSCALE),(bf16)(bb.y*QSCALE),
                                (bf16)(bb.z*QSCALE),(bf16)(bb.w*QSCALE)};
    }

    f32x16 oacc[2];
#pragma unroll
    for (int d = 0; d < 2; ++d)
#pragma unroll
        for (int rr = 0; rr < 16; ++rr) oacc[d][rr] = 0.f;
    float ps0 = 0.f, ps1 = 0.f, ps2 = 0.f, ps3 = 0.f;
    const float qh = (float)(qrow - 4 * hi);

    // ---- free-running band loop: this wave's parity tiles, no barriers ----
    for (int tc = tmin + par; tc <= tmax; tc += 2) {
        const int kv0 = tc * KVT;

        // K fragments direct from global (L1/L2-resident)
        bf16x8 kf[8];
#pragma unroll
        for (int blk = 0; blk < 2; ++blk)
#pragma unroll
            for (int dstep = 0; dstep < 4; ++dstep)
                kf[blk * 4 + dstep] =
                    *(const bf16x8*)(Kp + (size_t)(kv0 + blk * 32 + r32) * DH + dstep * 16 + hi * 8);

        // ---- S^T = K·Q^T (32x32x16): lane holds S^T[k][q=qrow] ----
        f32x16 sacc[2];
        __builtin_amdgcn_s_setprio(1);
#pragma unroll
        for (int blk = 0; blk < 2; ++blk) {
            f32x16 acc;
#pragma unroll
            for (int rr = 0; rr < 16; ++rr) acc[rr] = 0.f;
#pragma unroll
            for (int dstep = 0; dstep < 4; ++dstep)
                acc = __builtin_amdgcn_mfma_f32_32x32x16_bf16(kf[blk * 4 + dstep], qfrag[dstep], acc, 0, 0, 0);
            sacc[blk] = acc;
        }
        __builtin_amdgcn_s_setprio(0);

        // V fragments direct from global; softmax below covers their latency
        bf16x8 vf[8];
#pragma unroll
        for (int kstep = 0; kstep < 4; ++kstep)
#pragma unroll
            for (int dblk = 0; dblk < 2; ++dblk)
                vf[kstep * 2 + dblk] =
                    *(const bf16x8*)(Vp + (size_t)(dblk * 32 + r32) * SQ + kv0 + kstep * 16 + hi * 8);

        // ---- softmax, no max-tracking: p = exp2(s + bias) ----
        const float gq = qh - (float)kv0;
        float p[32];
#pragma unroll
        for (int blk = 0; blk < 2; ++blk)
#pragma unroll
            for (int reg = 0; reg < 16; ++reg) {
                const int krel = (reg & 3) + 8 * (reg >> 2) + 32 * blk;
                float d = gq - (float)krel;
                float s2 = fmaf(SLOPE2N, fabsf(d), sacc[blk][reg]);
                float e = fast_exp2(s2);
                p[blk * 16 + reg] = e;
                if ((reg & 3) == 0) ps0 += e;
                else if ((reg & 3) == 1) ps1 += e;
                else if ((reg & 3) == 2) ps2 += e;
                else ps3 += e;
            }

        // ---- PV: B-frag built in-register (cvt_pk + permlane32_swap) ----
        __builtin_amdgcn_s_setprio(1);
#pragma unroll
        for (int kstep = 0; kstep < 4; ++kstep) {
            const int b16 = (kstep >> 1) * 16;
            const int R = (kstep & 1) * 8;
            unsigned w0 = pkbf16(p[b16 + R + 0], p[b16 + R + 1]);
            unsigned w1 = pkbf16(p[b16 + R + 2], p[b16 + R + 3]);
            unsigned w2 = pkbf16(p[b16 + R + 4], p[b16 + R + 5]);
            unsigned w3 = pkbf16(p[b16 + R + 6], p[b16 + R + 7]);
            plswap(w0, w2);
            plswap(w1, w3);
            FragU pf; pf.u = (uint4v){w0, w1, w2, w3};
#pragma unroll
            for (int dblk = 0; dblk < 2; ++dblk)
                oacc[dblk] = __builtin_amdgcn_mfma_f32_32x32x16_bf16(vf[kstep * 2 + dblk], pf.b, oacc[dblk], 0, 0, 0);
        }
        __builtin_amdgcn_s_setprio(0);
    }

    // ---- combine parities: waves 2,3 hand (oacc, psum) to waves 0,1 via LDS ----
    float psum = (ps0 + ps1) + (ps2 + ps3);
    psum += __shfl_xor(psum, 32);

    float* slot = &ex[qhalf][lane][0];
    if (par == 1) {
#pragma unroll
        for (int dblk = 0; dblk < 2; ++dblk)
#pragma unroll
            for (int g2 = 0; g2 < 4; ++g2)
                *(float4*)(slot + dblk * 16 + g2 * 4) =
                    (float4){oacc[dblk][4*g2+0], oacc[dblk][4*g2+1],
                             oacc[dblk][4*g2+2], oacc[dblk][4*g2+3]};
        slot[32] = psum;
    }
    __syncthreads();
    if (par == 0) {
#pragma unroll
        for (int dblk = 0; dblk < 2; ++dblk)
#pragma unroll
            for (int g2 = 0; g2 < 4; ++g2) {
                float4 o = *(const float4*)(slot + dblk * 16 + g2 * 4);
                oacc[dblk][4*g2+0] += o.x; oacc[dblk][4*g2+1] += o.y;
                oacc[dblk][4*g2+2] += o.z; oacc[dblk][4*g2+3] += o.w;
            }
        psum += slot[32];

        const float inv = 1.f / psum;
#pragma unroll
        for (int dblk = 0; dblk < 2; ++dblk)
#pragma unroll
            for (int g2 = 0; g2 < 4; ++g2) {
                float4 o = {oacc[dblk][4*g2+0] * inv, oacc[dblk][4*g2+1] * inv,
                            oacc[dblk][4*g2+2] * inv, oacc[dblk][4*g2+3] * inv};
                *(float4*)(Op + (size_t)qrow * DH + dblk * 32 + g2 * 8 + hi * 4) = o;
            }
    }
}

extern "C" void kernel_launch(void* const* d_in, const int* in_sizes, int n_in,
                              void* d_out, int out_size, void* d_ws, size_t ws_size,
                              hipStream_t stream) {
    const float* q = (const float*)d_in[0];
    const float* k = (const float*)d_in[1];
    const float* v = (const float*)d_in[2];
    float* out = (float*)d_out;
    const int BH = in_sizes[0] / (SQ * DH);   // 32
    bf16* Kb  = (bf16*)d_ws;
    bf16* Vtb = (bf16*)((char*)d_ws + (size_t)BH * SQ * DH * sizeof(bf16));
    alibi_prep_kernel<<<dim3(SQ / 64, BH, 2), dim3(256), 0, stream>>>(k, v, Kb, Vtb);
    const int nblk = BH * (SQ / QBLK);        // 1024 work items (q-block, bh)
    alibi_attn_kernel<<<dim3(nblk), dim3(256), 0, stream>>>(q, Kb, Vtb, out);
}

// Round 9
// 60.524 us; speedup vs baseline: 1.5024x; 1.5024x over previous
//
#include <hip/hip_runtime.h>
#include <hip/hip_bf16.h>
#include <math.h>

typedef __bf16 bf16;
typedef __attribute__((ext_vector_type(8))) bf16 bf16x8;
typedef __attribute__((ext_vector_type(2))) bf16 bf16x2;
typedef __attribute__((ext_vector_type(16))) float f32x16;
typedef __attribute__((ext_vector_type(4))) unsigned int uint4v;

#define SQ 2048
#define DH 64
#define NH 16
#define KVT 64
#define NKVT (SQ / KVT)
#define LOG2E 1.44269504088896340736f

// LDS: 2 buffers; each = K [64][128B] @0 + Vt [64][128B] @8192 (16 KB)
#define PBUF  16384
#define LDSV  8192

__device__ __forceinline__ int swz(int row, int colbyte) {
    return row * 128 + (colbyte ^ ((row & 7) << 4));
}

__device__ __forceinline__ float fast_exp2(float x) {
#if __has_builtin(__builtin_amdgcn_exp2f)
    return __builtin_amdgcn_exp2f(x);
#else
    return exp2f(x);
#endif
}

__device__ __forceinline__ unsigned pkbf16(float a, float b) {
    union { bf16x2 h; unsigned u; } x;
    x.h = (bf16x2){(bf16)a, (bf16)b};
    return x.u;
}

// permlane32_swap: a' = [a.lo | b.lo], b' = [a.hi | b.hi]
#if __has_builtin(__builtin_amdgcn_permlane32_swap)
__device__ __forceinline__ void plswap(unsigned &a, unsigned &b) {
    typedef __attribute__((ext_vector_type(2))) unsigned int uint2v;
    uint2v r = __builtin_amdgcn_permlane32_swap(a, b, false, false);
    a = r[0]; b = r[1];
}
#else
__device__ __forceinline__ void plswap(unsigned &a, unsigned &b) {
    asm volatile("v_permlane32_swap_b32 %0, %1" : "+v"(a), "+v"(b));
}
#endif

#if __has_builtin(__builtin_amdgcn_global_load_lds)
#define HAVE_GLL 1
__device__ __forceinline__ void async_copy16(const bf16* g, char* l) {
    __builtin_amdgcn_global_load_lds(
        (const __attribute__((address_space(1))) unsigned int*)g,
        (__attribute__((address_space(3))) unsigned int*)l, 16, 0, 0);
}
#else
#define HAVE_GLL 0
#endif

union FragU { uint4v u; bf16x8 b; };

// ---------- prepass: K fp32 -> bf16 row-major; V fp32 -> V^T bf16 ----------
__global__ __launch_bounds__(256)
void alibi_prep_kernel(const float* __restrict__ K, const float* __restrict__ V,
                       bf16* __restrict__ Kb, bf16* __restrict__ Vtb) {
    __shared__ bf16 lt[64][72];
    const int t  = threadIdx.x;
    const int s0 = blockIdx.x * 64;
    const int bh = blockIdx.y;
    if (blockIdx.z == 0) {
        const float* src = K + (size_t)bh * SQ * DH + (size_t)s0 * DH;
        bf16* dst = Kb + (size_t)bh * SQ * DH + (size_t)s0 * DH;
#pragma unroll
        for (int i = 0; i < 2; ++i) {
            int idx = t + 256 * i;
            int row = idx >> 3, c8 = idx & 7;
            const float* p = src + row * DH + c8 * 8;
            float4 a = *(const float4*)p, b = *(const float4*)(p + 4);
            bf16x8 pk = {(bf16)a.x,(bf16)a.y,(bf16)a.z,(bf16)a.w,
                         (bf16)b.x,(bf16)b.y,(bf16)b.z,(bf16)b.w};
            *(bf16x8*)(dst + row * DH + c8 * 8) = pk;
        }
    } else {
        const float* src = V + (size_t)bh * SQ * DH + (size_t)s0 * DH;
#pragma unroll
        for (int i = 0; i < 2; ++i) {
            int idx = t + 256 * i;
            int row = idx >> 3, c8 = idx & 7;
            const float* p = src + row * DH + c8 * 8;
            float4 a = *(const float4*)p, b = *(const float4*)(p + 4);
            bf16 e[8] = {(bf16)a.x,(bf16)a.y,(bf16)a.z,(bf16)a.w,
                         (bf16)b.x,(bf16)b.y,(bf16)b.z,(bf16)b.w};
#pragma unroll
            for (int j = 0; j < 8; ++j) lt[c8 * 8 + j][row] = e[j];
        }
        __syncthreads();
        bf16* dst = Vtb + (size_t)bh * DH * SQ;
#pragma unroll
        for (int i = 0; i < 2; ++i) {
            int idx = t + 256 * i;
            int d = idx >> 3, c8 = idx & 7;
            *(bf16x8*)(dst + (size_t)d * SQ + s0 + c8 * 8) = *(const bf16x8*)&lt[d][c8 * 8];
        }
    }
}

// ---------- main attention kernel: 2-wave pair-blocks, XCD-pinned bh ----------
__global__ __launch_bounds__(128, 2)
void alibi_attn_kernel(const float* __restrict__ Q, const bf16* __restrict__ Kb,
                       const bf16* __restrict__ Vtb, float* __restrict__ Out) {
    __shared__ __align__(16) char lds[2 * PBUF];
    const int tid  = threadIdx.x;
    const int lane = tid & 63;
    const int wave = tid >> 6;      // 0: stages K + q-rows [0,32); 1: stages Vt + q-rows [32,64)
    const int r32  = lane & 31;
    const int hi   = lane >> 5;
    const int l8   = lane >> 3;

    // ---- XCD-pinned mapping: XCD x (= B&7 under round-robin) owns heads {x, 15-x},
    //      both batches (4 bh = 2 MB K/V, fits the 4 MiB per-XCD L2).
    //      CU gets slots {0..3} at one q-chunk: {b0,b1} x {heavy,light} -- balanced. ----
    const int B  = blockIdx.x;        // 0..1023
    const int x  = B & 7;
    const int j  = B >> 3;            // 0..127 within XCD
    const int sl = j >> 5;            // slot 0..3
    const int qc = j & 31;            // q-chunk (64 rows)
    const int h  = (sl < 2) ? (15 - x) : x;
    const int bh = (sl & 1) * NH + h;
    const int q0 = qc * 64;

    const float slope2  = exp2f(-0.5f * (float)(h + 1)) * LOG2E;
    const float SLOPE2N = -slope2;
    const float QSCALE  = 0.125f * LOG2E;

    // ---- ALiBi band: drop tiles with slope2*minDelta > 24 (rel err < 1e-5) ----
    const int D = (int)(24.0f / slope2);
    const int a0 = q0 - D;
    const int tmin = (a0 <= 0) ? 0 : (a0 >> 6);
    const int tmax = min(NKVT - 1, (q0 + 63 + D) >> 6);

    const size_t base = (size_t)bh * SQ * DH;
    const float* Qp = Q + base;
    const bf16*  Kp = Kb + base;
    const bf16*  Vp = Vtb + base;     // [DH][SQ]
    float*       Op = Out + base;

    // Q B-frag (pre-scaled): lane holds Q[q=qrow][dstep*16 + hi*8 + j]
    const int qrow = q0 + wave * 32 + r32;
    bf16x8 qfrag[4];
#pragma unroll
    for (int dstep = 0; dstep < 4; ++dstep) {
        const float* sq = Qp + (size_t)qrow * DH + dstep * 16 + hi * 8;
        float4 a = *(const float4*)sq, bb = *(const float4*)(sq + 4);
        qfrag[dstep] = (bf16x8){(bf16)(a.x*QSCALE),(bf16)(a.y*QSCALE),
                                (bf16)(a.z*QSCALE),(bf16)(a.w*QSCALE),
                                (bf16)(bb.x*QSCALE),(bf16)(bb.y*QSCALE),
                                (bf16)(bb.z*QSCALE),(bf16)(bb.w*QSCALE)};
    }

    f32x16 oacc[2];
#pragma unroll
    for (int d = 0; d < 2; ++d)
#pragma unroll
        for (int rr = 0; rr < 16; ++rr) oacc[d][rr] = 0.f;
    float ps0 = 0.f, ps1 = 0.f, ps2 = 0.f, ps3 = 0.f;
    const float qh = (float)(qrow - 4 * hi);

    const int cswz = ((lane & 7) << 4) ^ (l8 << 4);   // pre-swizzled source chunk

    auto STAGE = [&](int bufi, int kvtile) {
        char* sb = lds + bufi * PBUF + wave * LDSV;   // wave 0 -> K half, wave 1 -> Vt half
        const int kv0s = kvtile * KVT;
        if (wave == 0) {
#pragma unroll
            for (int c = 0; c < 8; ++c) {
                const int row = c * 8 + l8;
                const bf16* gK = Kp + (size_t)(kv0s + row) * DH + (cswz >> 1);
#if HAVE_GLL
                async_copy16(gK, sb + c * 1024);
#else
                *(bf16x8*)(sb + c * 1024 + lane * 16) = *(const bf16x8*)gK;
#endif
            }
        } else {
#pragma unroll
            for (int c = 0; c < 8; ++c) {
                const int row = c * 8 + l8;
                const bf16* gV = Vp + (size_t)row * SQ + kv0s + (cswz >> 1);
#if HAVE_GLL
                async_copy16(gV, sb + c * 1024);
#else
                *(bf16x8*)(sb + c * 1024 + lane * 16) = *(const bf16x8*)gV;
#endif
            }
        }
    };

    // prologue
    STAGE(0, tmin);
    asm volatile("s_waitcnt vmcnt(0)" ::: "memory");
    __builtin_amdgcn_s_barrier();
    __builtin_amdgcn_sched_barrier(0);

    int cur = 0;
    for (int t = tmin; t <= tmax; ++t) {
        if (t < tmax) STAGE(cur ^ 1, t + 1);          // issue next tile early
        const char* cbuf = lds + cur * PBUF;
        const int kv0 = t * KVT;

        // ---- S^T = K·Q^T (32x32x16): lane holds S^T[k][q=qrow] ----
        f32x16 sacc[2];
        __builtin_amdgcn_s_setprio(1);
#pragma unroll
        for (int blk = 0; blk < 2; ++blk) {
            f32x16 acc;
#pragma unroll
            for (int rr = 0; rr < 16; ++rr) acc[rr] = 0.f;
#pragma unroll
            for (int dstep = 0; dstep < 4; ++dstep) {
                bf16x8 kf = *(const bf16x8*)(cbuf + swz(blk * 32 + r32, dstep * 32 + hi * 16));
                acc = __builtin_amdgcn_mfma_f32_32x32x16_bf16(kf, qfrag[dstep], acc, 0, 0, 0);
            }
            sacc[blk] = acc;
        }
        __builtin_amdgcn_s_setprio(0);

        // ---- softmax, no max-tracking: p = exp2(s + bias) ----
        const float gq = qh - (float)kv0;
        float p[32];
#pragma unroll
        for (int blk = 0; blk < 2; ++blk)
#pragma unroll
            for (int reg = 0; reg < 16; ++reg) {
                const int krel = (reg & 3) + 8 * (reg >> 2) + 32 * blk;
                float d = gq - (float)krel;
                float s2 = fmaf(SLOPE2N, fabsf(d), sacc[blk][reg]);
                float e = fast_exp2(s2);
                p[blk * 16 + reg] = e;
                if ((reg & 3) == 0) ps0 += e;
                else if ((reg & 3) == 1) ps1 += e;
                else if ((reg & 3) == 2) ps2 += e;
                else ps3 += e;
            }

        // ---- PV: B-frag built in-register (cvt_pk + permlane32_swap) ----
        __builtin_amdgcn_s_setprio(1);
#pragma unroll
        for (int kstep = 0; kstep < 4; ++kstep) {
            const int b16 = (kstep >> 1) * 16;
            const int R = (kstep & 1) * 8;
            unsigned w0 = pkbf16(p[b16 + R + 0], p[b16 + R + 1]);
            unsigned w1 = pkbf16(p[b16 + R + 2], p[b16 + R + 3]);
            unsigned w2 = pkbf16(p[b16 + R + 4], p[b16 + R + 5]);
            unsigned w3 = pkbf16(p[b16 + R + 6], p[b16 + R + 7]);
            plswap(w0, w2);
            plswap(w1, w3);
            FragU pf; pf.u = (uint4v){w0, w1, w2, w3};
#pragma unroll
            for (int dblk = 0; dblk < 2; ++dblk) {
                bf16x8 vf = *(const bf16x8*)(cbuf + LDSV + swz(dblk * 32 + r32, kstep * 32 + hi * 16));
                oacc[dblk] = __builtin_amdgcn_mfma_f32_32x32x16_bf16(vf, pf.b, oacc[dblk], 0, 0, 0);
            }
        }
        __builtin_amdgcn_s_setprio(0);

        // ---- my stage landed; partner's too after barrier ----
        asm volatile("s_waitcnt vmcnt(0)" ::: "memory");
        __builtin_amdgcn_s_barrier();
        __builtin_amdgcn_sched_barrier(0);
        cur ^= 1;
    }

    // ---- epilogue: direct write, no cross-wave combine ----
    float psum = (ps0 + ps1) + (ps2 + ps3);
    psum += __shfl_xor(psum, 32);
    const float inv = 1.f / psum;
#pragma unroll
    for (int dblk = 0; dblk < 2; ++dblk)
#pragma unroll
        for (int g2 = 0; g2 < 4; ++g2) {
            float4 o = {oacc[dblk][4*g2+0] * inv, oacc[dblk][4*g2+1] * inv,
                        oacc[dblk][4*g2+2] * inv, oacc[dblk][4*g2+3] * inv};
            *(float4*)(Op + (size_t)qrow * DH + dblk * 32 + g2 * 8 + hi * 4) = o;
        }
}

extern "C" void kernel_launch(void* const* d_in, const int* in_sizes, int n_in,
                              void* d_out, int out_size, void* d_ws, size_t ws_size,
                              hipStream_t stream) {
    const float* q = (const float*)d_in[0];
    const float* k = (const float*)d_in[1];
    const float* v = (const float*)d_in[2];
    float* out = (float*)d_out;
    const int BH = in_sizes[0] / (SQ * DH);   // 32
    bf16* Kb  = (bf16*)d_ws;
    bf16* Vtb = (bf16*)((char*)d_ws + (size_t)BH * SQ * DH * sizeof(bf16));
    alibi_prep_kernel<<<dim3(SQ / 64, BH, 2), dim3(256), 0, stream>>>(k, v, Kb, Vtb);
    const int nblk = BH * (SQ / 64);          // 1024 pair-blocks
    alibi_attn_kernel<<<dim3(nblk), dim3(128), 0, stream>>>(q, Kb, Vtb, out);
}

// Round 11
// 50.147 us; speedup vs baseline: 1.8133x; 1.2069x over previous
//
#include <hip/hip_runtime.h>
#include <hip/hip_bf16.h>
#include <math.h>

typedef __bf16 bf16;
typedef __attribute__((ext_vector_type(8))) bf16 bf16x8;
typedef __attribute__((ext_vector_type(2))) bf16 bf16x2;
typedef __attribute__((ext_vector_type(16))) float f32x16;
typedef __attribute__((ext_vector_type(4))) unsigned int uint4v;

#define SQ 2048
#define DH 64
#define NH 16
#define KVT 32
#define NKVT (SQ / KVT)
#define LOG2E 1.44269504088896340736f

// Per-wave private LDS section: 8 KB = K tile [32][128B] @0 + packed Vt [32][128B] @4096.
// Packed Vt row r = { Vt[r][kv0..kv0+31] , Vt[r+32][kv0..kv0+31] } (two 64B halves).
#define WSEC 8192

__device__ __forceinline__ int swz(int row, int colbyte) {
    return row * 128 + (colbyte ^ ((row & 7) << 4));
}

__device__ __forceinline__ float fast_exp2(float x) {
#if __has_builtin(__builtin_amdgcn_exp2f)
    return __builtin_amdgcn_exp2f(x);
#else
    return exp2f(x);
#endif
}

__device__ __forceinline__ unsigned pkbf16(float a, float b) {
    union { bf16x2 h; unsigned u; } x;
    x.h = (bf16x2){(bf16)a, (bf16)b};
    return x.u;
}

// permlane32_swap: a' = [a.lo | b.lo], b' = [a.hi | b.hi]
#if __has_builtin(__builtin_amdgcn_permlane32_swap)
__device__ __forceinline__ void plswap(unsigned &a, unsigned &b) {
    typedef __attribute__((ext_vector_type(2))) unsigned int uint2v;
    uint2v r = __builtin_amdgcn_permlane32_swap(a, b, false, false);
    a = r[0]; b = r[1];
}
#else
__device__ __forceinline__ void plswap(unsigned &a, unsigned &b) {
    asm volatile("v_permlane32_swap_b32 %0, %1" : "+v"(a), "+v"(b));
}
#endif

#if __has_builtin(__builtin_amdgcn_global_load_lds)
#define HAVE_GLL 1
__device__ __forceinline__ void async_copy16(const bf16* g, char* l) {
    __builtin_amdgcn_global_load_lds(
        (const __attribute__((address_space(1))) unsigned int*)g,
        (__attribute__((address_space(3))) unsigned int*)l, 16, 0, 0);
}
#else
#define HAVE_GLL 0
#endif

union FragU { uint4v u; bf16x8 b; };

// ---------- prepass: K fp32 -> bf16 row-major; V fp32 -> V^T bf16 ----------
__global__ __launch_bounds__(256)
void alibi_prep_kernel(const float* __restrict__ K, const float* __restrict__ V,
                       bf16* __restrict__ Kb, bf16* __restrict__ Vtb) {
    __shared__ bf16 lt[64][72];
    const int t  = threadIdx.x;
    const int s0 = blockIdx.x * 64;
    const int bh = blockIdx.y;
    if (blockIdx.z == 0) {
        const float* src = K + (size_t)bh * SQ * DH + (size_t)s0 * DH;
        bf16* dst = Kb + (size_t)bh * SQ * DH + (size_t)s0 * DH;
#pragma unroll
        for (int i = 0; i < 2; ++i) {
            int idx = t + 256 * i;
            int row = idx >> 3, c8 = idx & 7;
            const float* p = src + row * DH + c8 * 8;
            float4 a = *(const float4*)p, b = *(const float4*)(p + 4);
            bf16x8 pk = {(bf16)a.x,(bf16)a.y,(bf16)a.z,(bf16)a.w,
                         (bf16)b.x,(bf16)b.y,(bf16)b.z,(bf16)b.w};
            *(bf16x8*)(dst + row * DH + c8 * 8) = pk;
        }
    } else {
        const float* src = V + (size_t)bh * SQ * DH + (size_t)s0 * DH;
#pragma unroll
        for (int i = 0; i < 2; ++i) {
            int idx = t + 256 * i;
            int row = idx >> 3, c8 = idx & 7;
            const float* p = src + row * DH + c8 * 8;
            float4 a = *(const float4*)p, b = *(const float4*)(p + 4);
            bf16 e[8] = {(bf16)a.x,(bf16)a.y,(bf16)a.z,(bf16)a.w,
                         (bf16)b.x,(bf16)b.y,(bf16)b.z,(bf16)b.w};
#pragma unroll
            for (int j = 0; j < 8; ++j) lt[c8 * 8 + j][row] = e[j];
        }
        __syncthreads();
        bf16* dst = Vtb + (size_t)bh * DH * SQ;
#pragma unroll
        for (int i = 0; i < 2; ++i) {
            int idx = t + 256 * i;
            int d = idx >> 3, c8 = idx & 7;
            *(bf16x8*)(dst + (size_t)d * SQ + s0 + c8 * 8) = *(const bf16x8*)&lt[d][c8 * 8];
        }
    }
}

// ---------- main attention: per-wave-independent KVT=32 tiles, zero in-loop barriers ----------
__global__ __launch_bounds__(256, 4)
void alibi_attn_kernel(const float* __restrict__ Q, const bf16* __restrict__ Kb,
                       const bf16* __restrict__ Vtb, float* __restrict__ Out) {
    __shared__ __align__(16) char lds[4 * WSEC];
    const int tid  = threadIdx.x;
    const int lane = tid & 63;
    const int wave = tid >> 6;
    const int pairIdx = wave >> 1;   // which 32-q chunk of the block's 64 rows
    const int par     = wave & 1;    // KV tile parity this wave owns
    const int r32  = lane & 31;
    const int hi   = lane >> 5;
    const int l8   = lane >> 3;
    const int cp   = (lane & 7) ^ l8;          // pre-swizzled source chunk index

    // ---- XCD-pinned mapping (R9, proven): XCD x owns heads {x, 15-x}, both batches ----
    const int B  = blockIdx.x;        // 0..1023
    const int x  = B & 7;
    const int j  = B >> 3;            // 0..127 within XCD
    const int sl = j >> 5;            // slot 0..3
    const int qc = j & 31;            // q-chunk (64 rows)
    const int h  = (sl < 2) ? (15 - x) : x;
    const int bh = (sl & 1) * NH + h;
    const int q0 = qc * 64;

    const float slope2  = exp2f(-0.5f * (float)(h + 1)) * LOG2E;
    const float SLOPE2N = -slope2;
    const float QSCALE  = 0.125f * LOG2E;

    // ---- ALiBi band (tiles of 32): drop tiles with slope2*minDelta > 24 ----
    const int D = (int)(24.0f / slope2);
    const int a0 = q0 - D;
    const int tmin = (a0 <= 0) ? 0 : (a0 >> 5);
    const int tmax = min(NKVT - 1, (q0 + 63 + D) >> 5);

    const size_t base = (size_t)bh * SQ * DH;
    const float* Qp = Q + base;
    const bf16*  Kp = Kb + base;
    const bf16*  Vp = Vtb + base;     // [DH][SQ]
    float*       Op = Out + base;

    // Q B-frag (pre-scaled): lane holds Q[q=qrow][ds*16 + hi*8 + j]
    const int qrow = q0 + pairIdx * 32 + r32;
    bf16x8 qfrag[4];
#pragma unroll
    for (int ds = 0; ds < 4; ++ds) {
        const float* sq = Qp + (size_t)qrow * DH + ds * 16 + hi * 8;
        float4 a = *(const float4*)sq, bb = *(const float4*)(sq + 4);
        qfrag[ds] = (bf16x8){(bf16)(a.x*QSCALE),(bf16)(a.y*QSCALE),
                             (bf16)(a.z*QSCALE),(bf16)(a.w*QSCALE),
                             (bf16)(bb.x*QSCALE),(bf16)(bb.y*QSCALE),
                             (bf16)(bb.z*QSCALE),(bf16)(bb.w*QSCALE)};
    }

    f32x16 oacc[2];
#pragma unroll
    for (int d = 0; d < 2; ++d)
#pragma unroll
        for (int rr = 0; rr < 16; ++rr) oacc[d][rr] = 0.f;
    float ps0 = 0.f, ps1 = 0.f, ps2 = 0.f, ps3 = 0.f;
    const float qh = (float)(qrow - 4 * hi);

    char* const sbuf = lds + wave * WSEC;     // this wave's private 8 KB section

    auto STAGE = [&](int kvtile) {
        const int kv0s = kvtile * KVT;
#pragma unroll
        for (int g = 0; g < 4; ++g) {         // K: rows kv0s+g*8+l8, full 128B row
            const bf16* gK = Kp + (size_t)(kv0s + g * 8 + l8) * DH + cp * 8;
#if HAVE_GLL
            async_copy16(gK, sbuf + g * 1024);
#else
            *(bf16x8*)(sbuf + g * 1024 + lane * 16) = *(const bf16x8*)gK;
#endif
        }
#pragma unroll
        for (int g = 0; g < 4; ++g) {         // packed Vt: row r = g*8+l8 holds d=r and d=r+32
            const int r = g * 8 + l8;
            const bf16* gV = Vp + (size_t)(r + 32 * (cp >> 2)) * SQ + kv0s + (cp & 3) * 8;
#if HAVE_GLL
            async_copy16(gV, sbuf + 4096 + g * 1024);
#else
            *(bf16x8*)(sbuf + 4096 + g * 1024 + lane * 16) = *(const bf16x8*)gV;
#endif
        }
    };

    // ---- zero-barrier pipelined band loop over my parity's tiles ----
    int t = tmin + par;
    if (t <= tmax) {
        STAGE(t);
        asm volatile("s_waitcnt vmcnt(0)" ::: "memory");
        __builtin_amdgcn_sched_barrier(0);
    }
    for (; t <= tmax; t += 2) {
        const int kv0 = t * KVT;

        // frags LDS -> regs (private section, conflict-free swizzle)
        bf16x8 kf[4], vf[4];
#pragma unroll
        for (int ds = 0; ds < 4; ++ds)
            kf[ds] = *(const bf16x8*)(sbuf + swz(r32, ds * 32 + hi * 16));
#pragma unroll
        for (int dblk = 0; dblk < 2; ++dblk)
#pragma unroll
            for (int ks = 0; ks < 2; ++ks)
                vf[dblk * 2 + ks] = *(const bf16x8*)(sbuf + 4096 + swz(r32, (dblk * 4 + ks * 2 + hi) * 16));
        asm volatile("s_waitcnt lgkmcnt(0)" ::: "memory");   // WAR fence: reads done before restage
        __builtin_amdgcn_sched_barrier(0);

        if (t + 2 <= tmax) STAGE(t + 2);     // overwrite my buffer for next tile

        // ---- S^T = K·Q^T : lane holds S^T[kv=(reg&3)+8*(reg>>2)+4hi][q=qrow] ----
        f32x16 sacc;
#pragma unroll
        for (int rr = 0; rr < 16; ++rr) sacc[rr] = 0.f;
        __builtin_amdgcn_s_setprio(1);
#pragma unroll
        for (int ds = 0; ds < 4; ++ds)
            sacc = __builtin_amdgcn_mfma_f32_32x32x16_bf16(kf[ds], qfrag[ds], sacc, 0, 0, 0);
        __builtin_amdgcn_s_setprio(0);

        // ---- softmax, no max-tracking: p = exp2(s + bias) ----
        const float gq = qh - (float)kv0;
        float p[16];
#pragma unroll
        for (int reg = 0; reg < 16; ++reg) {
            const int krel = (reg & 3) + 8 * (reg >> 2);
            float d = gq - (float)krel;
            float s2 = fmaf(SLOPE2N, fabsf(d), sacc[reg]);
            float e = fast_exp2(s2);
            p[reg] = e;
            if ((reg & 3) == 0) ps0 += e;
            else if ((reg & 3) == 1) ps1 += e;
            else if ((reg & 3) == 2) ps2 += e;
            else ps3 += e;
        }

        // ---- PV: B-frag in-register (cvt_pk + permlane32_swap) ----
        __builtin_amdgcn_s_setprio(1);
#pragma unroll
        for (int ks = 0; ks < 2; ++ks) {
            unsigned u0 = pkbf16(p[8 * ks + 0], p[8 * ks + 1]);
            unsigned u1 = pkbf16(p[8 * ks + 2], p[8 * ks + 3]);
            unsigned v0 = pkbf16(p[8 * ks + 4], p[8 * ks + 5]);
            unsigned v1 = pkbf16(p[8 * ks + 6], p[8 * ks + 7]);
            plswap(u0, v0);
            plswap(u1, v1);
            FragU pf; pf.u = (uint4v){u0, u1, v0, v1};
#pragma unroll
            for (int dblk = 0; dblk < 2; ++dblk)
                oacc[dblk] = __builtin_amdgcn_mfma_f32_32x32x16_bf16(vf[dblk * 2 + ks], pf.b, oacc[dblk], 0, 0, 0);
        }
        __builtin_amdgcn_s_setprio(0);

        // next tile's loads must have landed before the next ds_reads
        asm volatile("s_waitcnt vmcnt(0)" ::: "memory");
        __builtin_amdgcn_sched_barrier(0);
    }

    // ---- parity combine ----
    // BARRIER FIRST: exchange region aliases partner waves' live K/V sections (R10's NaN race).
    __syncthreads();

    float psum = (ps0 + ps1) + (ps2 + ps3);
    psum += __shfl_xor(psum, 32);

    float* region = (float*)(lds + pairIdx * 2 * WSEC);
    if (par == 1) {
        float* slot = region + lane * 32;
#pragma unroll
        for (int dblk = 0; dblk < 2; ++dblk)
#pragma unroll
            for (int g2 = 0; g2 < 4; ++g2)
                *(float4*)(slot + dblk * 16 + g2 * 4) =
                    (float4){oacc[dblk][4*g2+0], oacc[dblk][4*g2+1],
                             oacc[dblk][4*g2+2], oacc[dblk][4*g2+3]};
        region[2048 + lane] = psum;
    }
    __syncthreads();
    if (par == 0) {
        const float* slot = region + lane * 32;
#pragma unroll
        for (int dblk = 0; dblk < 2; ++dblk)
#pragma unroll
            for (int g2 = 0; g2 < 4; ++g2) {
                float4 o = *(const float4*)(slot + dblk * 16 + g2 * 4);
                oacc[dblk][4*g2+0] += o.x; oacc[dblk][4*g2+1] += o.y;
                oacc[dblk][4*g2+2] += o.z; oacc[dblk][4*g2+3] += o.w;
            }
        psum += region[2048 + lane];

        const float inv = 1.f / psum;
#pragma unroll
        for (int dblk = 0; dblk < 2; ++dblk)
#pragma unroll
            for (int g2 = 0; g2 < 4; ++g2) {
                float4 o = {oacc[dblk][4*g2+0] * inv, oacc[dblk][4*g2+1] * inv,
                            oacc[dblk][4*g2+2] * inv, oacc[dblk][4*g2+3] * inv};
                *(float4*)(Op + (size_t)qrow * DH + dblk * 32 + g2 * 8 + hi * 4) = o;
            }
    }
}

extern "C" void kernel_launch(void* const* d_in, const int* in_sizes, int n_in,
                              void* d_out, int out_size, void* d_ws, size_t ws_size,
                              hipStream_t stream) {
    const float* q = (const float*)d_in[0];
    const float* k = (const float*)d_in[1];
    const float* v = (const float*)d_in[2];
    float* out = (float*)d_out;
    const int BH = in_sizes[0] / (SQ * DH);   // 32
    bf16* Kb  = (bf16*)d_ws;
    bf16* Vtb = (bf16*)((char*)d_ws + (size_t)BH * SQ * DH * sizeof(bf16));
    alibi_prep_kernel<<<dim3(SQ / 64, BH, 2), dim3(256), 0, stream>>>(k, v, Kb, Vtb);
    const int nblk = BH * (SQ / 64);          // 1024 blocks (bh, 64 q rows)
    alibi_attn_kernel<<<dim3(nblk), dim3(256), 0, stream>>>(q, Kb, Vtb, out);
}